// Round 1
// baseline (2281.888 us; speedup 1.0000x reference)
//
#include <hip/hip_runtime.h>
#include <hip/hip_bf16.h>

#define VOCAB 32000
#define HIDDEN 1024
#define BATCH 32
#define SEQ 128

typedef short bf8v __attribute__((ext_vector_type(8)));   // 8 x bf16 payload
typedef float f32x4 __attribute__((ext_vector_type(4)));

static __device__ __forceinline__ short f2bf(float f) {
    return __builtin_bit_cast(short, __float2bfloat16(f));
}
static __device__ __forceinline__ float bf2f(short s) {
    unsigned u = ((unsigned)(unsigned short)s) << 16;
    return __builtin_bit_cast(float, u);
}

// -------- Phase 0: transpose f32 (K rows x N cols) -> bf16 (N rows x K cols) ----
__global__ __launch_bounds__(256) void transpose_f32_bf16(
    const float* __restrict__ in, short* __restrict__ out, int K, int N) {
    __shared__ short tile[64][65];
    int ntiles = N >> 6;
    int bn = blockIdx.x % ntiles;
    int bk = blockIdx.x / ntiles;
    int tid = threadIdx.x;
#pragma unroll
    for (int i = 0; i < 16; ++i) {
        int idx = i * 256 + tid;
        int lk = idx >> 6;   // local k
        int ln = idx & 63;   // local n  (consecutive tid -> coalesced read)
        float v = in[(size_t)(bk * 64 + lk) * N + (bn * 64 + ln)];
        tile[ln][lk] = f2bf(v);
    }
    __syncthreads();
#pragma unroll
    for (int i = 0; i < 16; ++i) {
        int idx = i * 256 + tid;
        int lnr = idx >> 6;  // local n (out row)
        int lkc = idx & 63;  // local k (consecutive tid -> coalesced write)
        out[(size_t)(bn * 64 + lnr) * K + (bk * 64 + lkc)] = tile[lnr][lkc];
    }
}

__global__ __launch_bounds__(256) void f32_to_bf16_vec(
    const float* __restrict__ in, short* __restrict__ out, int n) {
    int i = blockIdx.x * 256 + threadIdx.x;
    if (i < n) out[i] = f2bf(in[i]);
}

// -------- Phase 1: one recurrence step -------------------------------------
// h_out = tanh(W_xh[idx_t] + prev @ W_hh + b_h), all (32,1024)
// One wave per block; block handles 16 output columns, M=32 (2 m-tiles).
__global__ __launch_bounds__(64) void rnn_step(
    const short* __restrict__ prev,    // (32,1024) bf16
    const short* __restrict__ WhhT,    // (1024 n, 1024 k) bf16
    const float* __restrict__ Wxh,     // (VOCAB, 1024) f32
    const float* __restrict__ bh,      // (1024) f32
    const int* __restrict__ x,         // (BATCH, SEQ) int32
    int t,
    short* __restrict__ h_out)         // (32,1024) bf16
{
    int lane = threadIdx.x;
    int ncol0 = blockIdx.x * 16;
    int lrow = lane & 15;
    int kg = lane >> 4;                // 0..3
    f32x4 acc0 = {0.f, 0.f, 0.f, 0.f};
    f32x4 acc1 = {0.f, 0.f, 0.f, 0.f};
    const short* aBase = prev + lrow * HIDDEN + kg * 8;
    const short* bBase = WhhT + (size_t)(ncol0 + lrow) * HIDDEN + kg * 8;
#pragma unroll 4
    for (int kk = 0; kk < HIDDEN; kk += 32) {
        bf8v a0 = *(const bf8v*)(aBase + kk);
        bf8v a1 = *(const bf8v*)(aBase + 16 * HIDDEN + kk);
        bf8v b  = *(const bf8v*)(bBase + kk);
        acc0 = __builtin_amdgcn_mfma_f32_16x16x32_bf16(a0, b, acc0, 0, 0, 0);
        acc1 = __builtin_amdgcn_mfma_f32_16x16x32_bf16(a1, b, acc1, 0, 0, 0);
    }
    // D mapping: col = lane&15, row = (lane>>4)*4 + r
    int col = ncol0 + lrow;
    float bias = bh[col];
#pragma unroll
    for (int r = 0; r < 4; ++r) {
        int row0 = kg * 4 + r;         // m-tile 0: batch rows 0..15
        {
            int idx = x[row0 * SEQ + t];
            float v = tanhf(Wxh[(size_t)idx * HIDDEN + col] + acc0[r] + bias);
            h_out[row0 * HIDDEN + col] = f2bf(v);
        }
        int row1 = row0 + 16;          // m-tile 1: batch rows 16..31
        {
            int idx = x[row1 * SEQ + t];
            float v = tanhf(Wxh[(size_t)idx * HIDDEN + col] + acc1[r] + bias);
            h_out[row1 * HIDDEN + col] = f2bf(v);
        }
    }
}

// -------- Phase 2: big output GEMM  C = H @ W_ho^T(T) + b_o -----------------
// A: (4096,1024) bf16 row-major; B: (32000,1024) bf16 row-major (N x K);
// C: (4096,32000) f32.  128x128 tile, BK=32, 4 waves (2x2), 64x64 per wave.
#define LDSTRIDE 40   // 32 + 8 pad: breaks the stride-64B bank pattern
__global__ __launch_bounds__(256) void gemm_out(
    const short* __restrict__ A,
    const short* __restrict__ B,
    const float* __restrict__ bo,
    float* __restrict__ C)
{
    __shared__ short As[128 * LDSTRIDE];
    __shared__ short Bs[128 * LDSTRIDE];

    // XCD-aware swizzle (grid 8000, 8000 % 8 == 0 -> bijective)
    int nwg = gridDim.x;
    int cpx = nwg >> 3;
    int bid = blockIdx.x;
    int swz = (bid & 7) * cpx + (bid >> 3);
    int bm = swz % 32;   // m fastest: consecutive blocks share the B panel
    int bn = swz / 32;

    int tid = threadIdx.x;
    int lane = tid & 63;
    int wid = tid >> 6;
    int wm = wid >> 1, wn = wid & 1;
    int lrow = lane & 15, kg = lane >> 4;

    f32x4 acc[4][4] = {};

    const size_t a_row0 = (size_t)bm * 128;
    const size_t b_row0 = (size_t)bn * 128;
    int r0 = tid >> 2;            // 0..63
    int c0 = (tid & 3) * 8;       // 0,8,16,24

    for (int kk = 0; kk < HIDDEN; kk += 32) {
        // stage to regs (issued before barrier -> overlaps prior MFMA phase)
        bf8v va0 = *(const bf8v*)&A[(a_row0 + r0) * HIDDEN + kk + c0];
        bf8v va1 = *(const bf8v*)&A[(a_row0 + 64 + r0) * HIDDEN + kk + c0];
        bf8v vb0 = *(const bf8v*)&B[(b_row0 + r0) * HIDDEN + kk + c0];
        bf8v vb1 = *(const bf8v*)&B[(b_row0 + 64 + r0) * HIDDEN + kk + c0];
        __syncthreads();   // previous iteration's ds_reads complete
        *(bf8v*)&As[r0 * LDSTRIDE + c0] = va0;
        *(bf8v*)&As[(64 + r0) * LDSTRIDE + c0] = va1;
        *(bf8v*)&Bs[r0 * LDSTRIDE + c0] = vb0;
        *(bf8v*)&Bs[(64 + r0) * LDSTRIDE + c0] = vb1;
        __syncthreads();

        bf8v af[4], bfr[4];
#pragma unroll
        for (int mi = 0; mi < 4; ++mi)
            af[mi] = *(const bf8v*)&As[(wm * 64 + mi * 16 + lrow) * LDSTRIDE + kg * 8];
#pragma unroll
        for (int nj = 0; nj < 4; ++nj)
            bfr[nj] = *(const bf8v*)&Bs[(wn * 64 + nj * 16 + lrow) * LDSTRIDE + kg * 8];
#pragma unroll
        for (int mi = 0; mi < 4; ++mi)
#pragma unroll
            for (int nj = 0; nj < 4; ++nj)
                acc[mi][nj] = __builtin_amdgcn_mfma_f32_16x16x32_bf16(
                    af[mi], bfr[nj], acc[mi][nj], 0, 0, 0);
    }

    // epilogue: D col = lane&15, row = (lane>>4)*4 + r
    size_t crow_base = a_row0 + wm * 64;
    int ccol_base = (int)b_row0 + wn * 64;
#pragma unroll
    for (int nj = 0; nj < 4; ++nj) {
        int col = ccol_base + nj * 16 + lrow;
        float bias = bo[col];
#pragma unroll
        for (int mi = 0; mi < 4; ++mi) {
#pragma unroll
            for (int r = 0; r < 4; ++r) {
                size_t row = crow_base + mi * 16 + kg * 4 + r;
                C[row * VOCAB + col] = acc[mi][nj][r] + bias;
            }
        }
    }
}

// -------- final_state: bf16 h_127 -> f32 ------------------------------------
__global__ __launch_bounds__(256) void write_final(
    const short* __restrict__ Hlast, float* __restrict__ out) {
    int i = blockIdx.x * 256 + threadIdx.x;
    if (i < BATCH * HIDDEN) out[i] = bf2f(Hlast[i]);
}

extern "C" void kernel_launch(void* const* d_in, const int* in_sizes, int n_in,
                              void* d_out, int out_size, void* d_ws, size_t ws_size,
                              hipStream_t stream) {
    const int*   x   = (const int*)  d_in[0];
    const float* st  = (const float*)d_in[1];
    const float* Wxh = (const float*)d_in[2];
    const float* Whh = (const float*)d_in[3];
    const float* bh  = (const float*)d_in[4];
    const float* Who = (const float*)d_in[5];
    const float* bo  = (const float*)d_in[6];
    float* out = (float*)d_out;

    char* ws = (char*)d_ws;
    short* WhhT = (short*)ws;                                  // 2 MB
    short* WhoT = (short*)(ws + 2097152ull);                   // 65.536 MB
    short* H    = (short*)(ws + 2097152ull + 65536000ull);     // 8.389 MB
    short* S0   = (short*)(ws + 2097152ull + 65536000ull + 8388608ull); // 64 KB
    // total ~76 MB of d_ws

    transpose_f32_bf16<<<(1024/64)*(1024/64), 256, 0, stream>>>(Whh, WhhT, 1024, 1024);
    transpose_f32_bf16<<<(VOCAB/64)*(1024/64), 256, 0, stream>>>(Who, WhoT, 1024, VOCAB);
    f32_to_bf16_vec<<<(BATCH*HIDDEN + 255)/256, 256, 0, stream>>>(st, S0, BATCH*HIDDEN);

    for (int t = 0; t < SEQ; ++t) {
        const short* prev = (t == 0) ? S0 : H + (size_t)(t - 1) * BATCH * HIDDEN;
        rnn_step<<<HIDDEN/16, 64, 0, stream>>>(prev, WhhT, Wxh, bh, x, t,
                                               H + (size_t)t * BATCH * HIDDEN);
    }

    gemm_out<<<(4096/128) * (VOCAB/128), 256, 0, stream>>>(H, WhoT, bo, out);
    write_final<<<(BATCH*HIDDEN + 255)/256, 256, 0, stream>>>(
        H + (size_t)(SEQ - 1) * BATCH * HIDDEN, out + (size_t)SEQ * BATCH * VOCAB);
}

// Round 2
// 1999.209 us; speedup vs baseline: 1.1414x; 1.1414x over previous
//
#include <hip/hip_runtime.h>
#include <hip/hip_bf16.h>

#define VOCAB 32000
#define HIDDEN 1024
#define BATCH 32
#define SEQ 128
#define NBLK 64   // persistent-kernel block count (<= 256 CUs, co-resident)

typedef short bf8v __attribute__((ext_vector_type(8)));   // 8 x bf16 payload
typedef float f32x4 __attribute__((ext_vector_type(4)));

static __device__ __forceinline__ short f2bf(float f) {
    return __builtin_bit_cast(short, __float2bfloat16(f));
}
static __device__ __forceinline__ float bf2f(short s) {
    unsigned u = ((unsigned)(unsigned short)s) << 16;
    return __builtin_bit_cast(float, u);
}

// -------- Phase 0: transpose f32 (K rows x N cols) -> bf16 (N rows x K cols) ----
__global__ __launch_bounds__(256) void transpose_f32_bf16(
    const float* __restrict__ in, short* __restrict__ out, int K, int N) {
    __shared__ short tile[64][65];
    int ntiles = N >> 6;
    int bn = blockIdx.x % ntiles;
    int bk = blockIdx.x / ntiles;
    int tid = threadIdx.x;
#pragma unroll
    for (int i = 0; i < 16; ++i) {
        int idx = i * 256 + tid;
        int lk = idx >> 6;
        int ln = idx & 63;
        float v = in[(size_t)(bk * 64 + lk) * N + (bn * 64 + ln)];
        tile[ln][lk] = f2bf(v);
    }
    __syncthreads();
#pragma unroll
    for (int i = 0; i < 16; ++i) {
        int idx = i * 256 + tid;
        int lnr = idx >> 6;
        int lkc = idx & 63;
        out[(size_t)(bn * 64 + lnr) * K + (bk * 64 + lkc)] = tile[lnr][lkc];
    }
}

__global__ __launch_bounds__(256) void f32_to_bf16_vec(
    const float* __restrict__ in, short* __restrict__ out, int n) {
    int i = blockIdx.x * 256 + threadIdx.x;
    if (i < n) out[i] = f2bf(in[i]);
}

// -------- Phase 1: persistent recurrence kernel ------------------------------
// 64 blocks x 1 wave. Block b owns columns [b*16, b*16+16) of h.
// W_hh^T slice (16 rows x 1024 k, bf16) lives in LDS for the whole kernel
// (immune to the per-step L2 invalidation from __threadfence()).
// Cross-block h exchange through H[] with a global counter barrier.
__global__ __launch_bounds__(64) void rnn_persistent(
    const short* __restrict__ WhhT,   // (1024 n, 1024 k) bf16
    const float* __restrict__ Wxh,    // (VOCAB, 1024) f32
    const float* __restrict__ bh,     // (1024) f32
    const int*   __restrict__ x,      // (BATCH, SEQ) int32
    const short* __restrict__ S0,     // (32,1024) bf16 initial state
    short* __restrict__ H,            // (SEQ, 32, 1024) bf16
    unsigned int* __restrict__ bar)   // zeroed by memset each launch
{
    __shared__ short Wl[16 * 1024];   // 32 KB
    int lane = threadIdx.x;
    int ncol0 = blockIdx.x * 16;

    // Load W slice into LDS; XOR-swizzle 16B granules: phys_g = g ^ (row&7).
    // Reads in the k-loop then spread 64 lanes across all bank groups
    // (contiguous-footprint floor instead of 16-way conflict at stride 2048B).
    for (int i = lane; i < 16 * 128; i += 64) {
        int r = i >> 7;      // row 0..15
        int g = i & 127;     // 16B granule in row
        bf8v v = *(const bf8v*)(WhhT + ((size_t)(ncol0 + r) << 10) + g * 8);
        *(bf8v*)(Wl + r * 1024 + ((g ^ (r & 7)) << 3)) = v;
    }
    __syncthreads();

    int lrow = lane & 15, kg = lane >> 4;
    int col = ncol0 + lrow;
    float bias = bh[col];
    int rx = lrow & 7;
    const short* wRow = Wl + lrow * 1024;

    // prefetch token ids for t=0
    int xc[8];
#pragma unroll
    for (int r = 0; r < 4; ++r) {
        xc[r]     = x[(kg * 4 + r) * SEQ];
        xc[r + 4] = x[(kg * 4 + r + 16) * SEQ];
    }

    for (int t = 0; t < SEQ; ++t) {
        // issue the random Wxh gathers early; consumed only in the epilogue,
        // so HBM latency hides under the MFMA loop + barrier.
        float wx[8];
#pragma unroll
        for (int r = 0; r < 8; ++r)
            wx[r] = Wxh[((size_t)xc[r] << 10) + col];
        // prefetch next step's token ids (clamped; dead at t==SEQ-1)
        int tn = (t + 1 < SEQ) ? (t + 1) : (SEQ - 1);
        int xn[8];
#pragma unroll
        for (int r = 0; r < 4; ++r) {
            xn[r]     = x[(kg * 4 + r) * SEQ + tn];
            xn[r + 4] = x[(kg * 4 + r + 16) * SEQ + tn];
        }

        const short* A = (t == 0) ? S0 : (H + ((size_t)(t - 1) << 15));
        const short* aBase = A + lrow * HIDDEN + kg * 8;
        f32x4 acc0 = {0.f, 0.f, 0.f, 0.f};
        f32x4 acc1 = {0.f, 0.f, 0.f, 0.f};
#pragma unroll 8
        for (int kk = 0; kk < HIDDEN; kk += 32) {
            bf8v a0 = *(const bf8v*)(aBase + kk);
            bf8v a1 = *(const bf8v*)(aBase + 16 * HIDDEN + kk);
            bf8v b  = *(const bf8v*)(wRow + ((((kk >> 3) + kg) ^ rx) << 3));
            acc0 = __builtin_amdgcn_mfma_f32_16x16x32_bf16(a0, b, acc0, 0, 0, 0);
            acc1 = __builtin_amdgcn_mfma_f32_16x16x32_bf16(a1, b, acc1, 0, 0, 0);
        }

        short* Ht = H + ((size_t)t << 15);
#pragma unroll
        for (int r = 0; r < 4; ++r) {
            int row0 = kg * 4 + r;     // D mapping: col=lane&15, row=(lane>>4)*4+r
            Ht[row0 * HIDDEN + col]        = f2bf(tanhf(wx[r]     + acc0[r] + bias));
            Ht[(row0 + 16) * HIDDEN + col] = f2bf(tanhf(wx[r + 4] + acc1[r] + bias));
        }
#pragma unroll
        for (int r = 0; r < 8; ++r) xc[r] = xn[r];

        // release: make our h-slice stores visible device-wide
        __threadfence();
        __syncthreads();
        if (lane == 0) {
            atomicAdd(bar, 1u);   // device-scope by default
            unsigned target = (unsigned)NBLK * (unsigned)(t + 1);
            while (__hip_atomic_load(bar, __ATOMIC_RELAXED,
                                     __HIP_MEMORY_SCOPE_AGENT) < target) {
                __builtin_amdgcn_s_sleep(1);
            }
        }
        __syncthreads();
        // acquire: invalidate stale L2 lines before reading others' h slices
        __threadfence();
    }
}

// -------- Phase 2: big output GEMM  C = H @ WhoT^T + b_o --------------------
// A: (4096,1024) bf16; B: (32000,1024) bf16 (N x K); C: (4096,32000) f32.
// 128x128 tile, BK=32, 4 waves (2x2), 64x64 per wave.
// LDSTRIDE=32 (64-B rows): both ds_write and ds_read footprints are
// contiguous 1KB/4KB blocks -> bank-conflict-free floor.
#define LDSTRIDE 32
__global__ __launch_bounds__(256) void gemm_out(
    const short* __restrict__ A,
    const short* __restrict__ B,
    const float* __restrict__ bo,
    float* __restrict__ C)
{
    __shared__ short As[128 * LDSTRIDE];
    __shared__ short Bs[128 * LDSTRIDE];

    // XCD-aware swizzle (grid 8000 % 8 == 0 -> bijective)
    int nwg = gridDim.x;
    int cpx = nwg >> 3;
    int bid = blockIdx.x;
    int swz = (bid & 7) * cpx + (bid >> 3);
    int bm = swz % 32;   // m fastest: consecutive blocks share the B panel
    int bn = swz / 32;

    int tid = threadIdx.x;
    int lane = tid & 63;
    int wid = tid >> 6;
    int wm = wid >> 1, wn = wid & 1;
    int lrow = lane & 15, kg = lane >> 4;

    f32x4 acc[4][4] = {};

    const size_t a_row0 = (size_t)bm * 128;
    const size_t b_row0 = (size_t)bn * 128;
    int r0 = tid >> 2;            // 0..63
    int c0 = (tid & 3) * 8;       // 0,8,16,24

    for (int kk = 0; kk < HIDDEN; kk += 32) {
        bf8v va0 = *(const bf8v*)&A[(a_row0 + r0) * HIDDEN + kk + c0];
        bf8v va1 = *(const bf8v*)&A[(a_row0 + 64 + r0) * HIDDEN + kk + c0];
        bf8v vb0 = *(const bf8v*)&B[(b_row0 + r0) * HIDDEN + kk + c0];
        bf8v vb1 = *(const bf8v*)&B[(b_row0 + 64 + r0) * HIDDEN + kk + c0];
        __syncthreads();
        *(bf8v*)&As[r0 * LDSTRIDE + c0] = va0;
        *(bf8v*)&As[(64 + r0) * LDSTRIDE + c0] = va1;
        *(bf8v*)&Bs[r0 * LDSTRIDE + c0] = vb0;
        *(bf8v*)&Bs[(64 + r0) * LDSTRIDE + c0] = vb1;
        __syncthreads();

        bf8v af[4], bfr[4];
#pragma unroll
        for (int mi = 0; mi < 4; ++mi)
            af[mi] = *(const bf8v*)&As[(wm * 64 + mi * 16 + lrow) * LDSTRIDE + kg * 8];
#pragma unroll
        for (int nj = 0; nj < 4; ++nj)
            bfr[nj] = *(const bf8v*)&Bs[(wn * 64 + nj * 16 + lrow) * LDSTRIDE + kg * 8];
#pragma unroll
        for (int mi = 0; mi < 4; ++mi)
#pragma unroll
            for (int nj = 0; nj < 4; ++nj)
                acc[mi][nj] = __builtin_amdgcn_mfma_f32_16x16x32_bf16(
                    af[mi], bfr[nj], acc[mi][nj], 0, 0, 0);
    }

    size_t crow_base = a_row0 + wm * 64;
    int ccol_base = (int)b_row0 + wn * 64;
#pragma unroll
    for (int nj = 0; nj < 4; ++nj) {
        int col = ccol_base + nj * 16 + lrow;
        float bias = bo[col];
#pragma unroll
        for (int mi = 0; mi < 4; ++mi) {
#pragma unroll
            for (int r = 0; r < 4; ++r) {
                size_t row = crow_base + mi * 16 + kg * 4 + r;
                C[row * VOCAB + col] = acc[mi][nj][r] + bias;
            }
        }
    }
}

// -------- final_state: bf16 h_127 -> f32 ------------------------------------
__global__ __launch_bounds__(256) void write_final(
    const short* __restrict__ Hlast, float* __restrict__ out) {
    int i = blockIdx.x * 256 + threadIdx.x;
    if (i < BATCH * HIDDEN) out[i] = bf2f(Hlast[i]);
}

extern "C" void kernel_launch(void* const* d_in, const int* in_sizes, int n_in,
                              void* d_out, int out_size, void* d_ws, size_t ws_size,
                              hipStream_t stream) {
    const int*   x   = (const int*)  d_in[0];
    const float* st  = (const float*)d_in[1];
    const float* Wxh = (const float*)d_in[2];
    const float* Whh = (const float*)d_in[3];
    const float* bh  = (const float*)d_in[4];
    const float* Who = (const float*)d_in[5];
    const float* bo  = (const float*)d_in[6];
    float* out = (float*)d_out;

    char* ws = (char*)d_ws;
    short* WhhT = (short*)ws;                                           // 2 MB
    short* WhoT = (short*)(ws + 2097152ull);                            // 65.536 MB
    short* H    = (short*)(ws + 2097152ull + 65536000ull);              // 8.389 MB
    short* S0   = (short*)(ws + 2097152ull + 65536000ull + 8388608ull); // 64 KB
    unsigned int* bar = (unsigned int*)(ws + 2097152ull + 65536000ull + 8388608ull + 65536ull);

    transpose_f32_bf16<<<(1024/64)*(1024/64), 256, 0, stream>>>(Whh, WhhT, 1024, 1024);
    transpose_f32_bf16<<<(VOCAB/64)*(1024/64), 256, 0, stream>>>(Who, WhoT, 1024, VOCAB);
    f32_to_bf16_vec<<<(BATCH*HIDDEN + 255)/256, 256, 0, stream>>>(st, S0, BATCH*HIDDEN);
    hipMemsetAsync(bar, 0, sizeof(unsigned int), stream);

    rnn_persistent<<<NBLK, 64, 0, stream>>>(WhhT, Wxh, bh, x, S0, H, bar);

    gemm_out<<<(4096/128) * (VOCAB/128), 256, 0, stream>>>(H, WhoT, bo, out);
    write_final<<<(BATCH*HIDDEN + 255)/256, 256, 0, stream>>>(
        H + (size_t)(SEQ - 1) * BATCH * HIDDEN, out + (size_t)SEQ * BATCH * VOCAB);
}

// Round 4
// 1183.415 us; speedup vs baseline: 1.9282x; 1.6894x over previous
//
#include <hip/hip_runtime.h>
#include <hip/hip_bf16.h>

#define VOCAB 32000
#define HIDDEN 1024
#define BATCH 32
#define SEQ 128
#define NBLK 32   // persistent blocks x 256 threads; all trivially co-resident

typedef short bf8v __attribute__((ext_vector_type(8)));   // 8 x bf16 payload
typedef float f32x4 __attribute__((ext_vector_type(4)));
typedef unsigned long long u64;

static __device__ __forceinline__ short f2bf(float f) {
    return __builtin_bit_cast(short, __float2bfloat16(f));
}
static __device__ __forceinline__ float bf2f(short s) {
    unsigned u = ((unsigned)(unsigned short)s) << 16;
    return __builtin_bit_cast(float, u);
}

// -------- Phase 0: transpose f32 (K rows x N cols) -> bf16 (N rows x K cols) ----
__global__ __launch_bounds__(256) void transpose_f32_bf16(
    const float* __restrict__ in, short* __restrict__ out, int K, int N) {
    __shared__ short tile[64][65];
    int ntiles = N >> 6;
    int bn = blockIdx.x % ntiles;
    int bk = blockIdx.x / ntiles;
    int tid = threadIdx.x;
#pragma unroll
    for (int i = 0; i < 16; ++i) {
        int idx = i * 256 + tid;
        int lk = idx >> 6;
        int ln = idx & 63;
        float v = in[(size_t)(bk * 64 + lk) * N + (bn * 64 + ln)];
        tile[ln][lk] = f2bf(v);
    }
    __syncthreads();
#pragma unroll
    for (int i = 0; i < 16; ++i) {
        int idx = i * 256 + tid;
        int lnr = idx >> 6;
        int lkc = idx & 63;
        out[(size_t)(bn * 64 + lnr) * K + (bk * 64 + lkc)] = tile[lnr][lkc];
    }
}

__global__ __launch_bounds__(256) void f32_to_bf16_vec(
    const float* __restrict__ in, short* __restrict__ out, int n) {
    int i = blockIdx.x * 256 + threadIdx.x;
    if (i < n) out[i] = f2bf(in[i]);
}

// -------- Phase 1: persistent recurrence, agent-atomic h exchange ------------
// 32 blocks x 256 threads (4 waves). Block b owns h columns [b*32, b*32+32).
// Waves: (wm,wn) = (wid>>1, wid&1): 16x16 output tile each.
// Exchange protocol per step: every lane atomic-stores 1 u64 of the slice
// (AGENT scope -> coherent at MALL), vmcnt(0), counter barrier (atomic RMW +
// atomic poll), then every lane atomic-loads 32 u64 of the full h_t (AGENT
// scope -> reads MALL, immune to stale L1/L2) into XOR-swizzled LDS.
// No cache-wide fences anywhere -> Wxh/x/WhhT stay warm in L2.
__global__ __launch_bounds__(256) void rnn_persistent(
    const short* __restrict__ WhhT,   // (1024 n, 1024 k) bf16
    const float* __restrict__ Wxh,    // (VOCAB, 1024) f32
    const float* __restrict__ bh,     // (1024) f32
    const int*   __restrict__ x,      // (BATCH, SEQ) int32
    const short* __restrict__ S0,     // (32,1024) bf16 initial state
    short* __restrict__ H,            // (SEQ, 32, 1024) bf16
    unsigned int* __restrict__ bar)   // zeroed by memset each launch
{
    __shared__ short Wl[32 * 1024];    // 64 KB, XOR-swizzled 16B granules
    __shared__ short hl[32 * 1024];    // 64 KB, XOR-swizzled 16B granules
    __shared__ short hstage[32 * 32];  // 2 KB slice repack
    const int tid = threadIdx.x;
    const int ncol0 = blockIdx.x * 32;

    // W slice -> LDS (logical granule g of row r stored at phys g^(r&7))
    for (int i = tid; i < 32 * 128; i += 256) {
        int r = i >> 7, g = i & 127;
        bf8v w = *(const bf8v*)(WhhT + ((size_t)(ncol0 + r) << 10) + (g << 3));
        *(bf8v*)(Wl + (r << 10) + ((g ^ (r & 7)) << 3)) = w;
    }
    // initial h = S0 -> hl (atomic path harmless here, keeps one code shape)
    {
        u64 v[32];
#pragma unroll
        for (int i = 0; i < 32; ++i)
            v[i] = __hip_atomic_load((u64*)(S0 + (i << 10)) + tid,
                                     __ATOMIC_RELAXED, __HIP_MEMORY_SCOPE_AGENT);
        int g = tid >> 1, hf = tid & 1;
#pragma unroll
        for (int i = 0; i < 32; ++i)
            *(u64*)((char*)hl + (i << 11) + (((g ^ (i & 7)) << 4) | (hf << 3))) = v[i];
    }
    __syncthreads();

    const int lane = tid & 63, wid = tid >> 6;
    const int wm = wid >> 1, wn = wid & 1;
    const int lrow = lane & 15, kg = lane >> 4;
    const int rx = lrow & 7;
    const short* aRow = hl + ((wm * 16 + lrow) << 10);
    const short* bRow = Wl + ((wn * 16 + lrow) << 10);
    const int colg = ncol0 + wn * 16 + lrow;     // global h-column this lane owns
    const float bias = bh[colg];

    // token ids + Wxh gathers for t=0
    int xc[4];
    float wx[4];
#pragma unroll
    for (int r = 0; r < 4; ++r) {
        xc[r] = x[(wm * 16 + kg * 4 + r) * SEQ];
        wx[r] = Wxh[((size_t)xc[r] << 10) + colg];
    }

    for (int t = 0; t < SEQ; ++t) {
        int tn = (t + 1 < SEQ) ? t + 1 : SEQ - 1;
        int xn[4];
#pragma unroll
        for (int r = 0; r < 4; ++r)
            xn[r] = x[(wm * 16 + kg * 4 + r) * SEQ + tn];

        f32x4 acc = {0.f, 0.f, 0.f, 0.f};
#pragma unroll 8
        for (int kk = 0; kk < HIDDEN; kk += 32) {
            int gb = (kk >> 3) + kg;
            int sw = (gb ^ rx) << 3;
            bf8v a = *(const bf8v*)(aRow + sw);
            bf8v b = *(const bf8v*)(bRow + sw);
            acc = __builtin_amdgcn_mfma_f32_16x16x32_bf16(a, b, acc, 0, 0, 0);
        }

        // epilogue -> hstage (D map: col=lane&15, row=(lane>>4)*4+r)
#pragma unroll
        for (int r = 0; r < 4; ++r) {
            int row = wm * 16 + kg * 4 + r;
            hstage[row * 32 + wn * 16 + lrow] = f2bf(tanhf(wx[r] + acc[r] + bias));
        }
        __syncthreads();

        // write-through our slice: exactly 1 u64 per lane
        {
            int sr = tid >> 3, sc = tid & 7;
            u64 d = *(const u64*)(hstage + sr * 32 + sc * 4);
            u64* dst = (u64*)(H + ((size_t)t << 15) + (sr << 10) + ncol0) + sc;
            __hip_atomic_store(dst, d, __ATOMIC_RELAXED, __HIP_MEMORY_SCOPE_AGENT);
        }
        asm volatile("s_waitcnt vmcnt(0)" ::: "memory");  // slice at coherence point
        __syncthreads();                                   // all 4 waves ack'd

        if (tid == 0) {
            __hip_atomic_fetch_add(bar, 1u, __ATOMIC_RELAXED, __HIP_MEMORY_SCOPE_AGENT);
            unsigned target = (unsigned)NBLK * (unsigned)(t + 1);
            while (__hip_atomic_load(bar, __ATOMIC_RELAXED, __HIP_MEMORY_SCOPE_AGENT) < target)
                __builtin_amdgcn_s_sleep(1);
        }
        __syncthreads();

        // Wxh gathers for t+1: issued now so HBM latency hides under the
        // reload (one MALL round-trip) + next MFMA phase.
#pragma unroll
        for (int r = 0; r < 4; ++r) {
            xc[r] = xn[r];
            wx[r] = Wxh[((size_t)xc[r] << 10) + colg];
        }

        // reload full h_t -> hl via agent-scope atomic loads (coherent)
        if (t + 1 < SEQ) {
            const short* Ht = H + ((size_t)t << 15);
            u64 v[32];
#pragma unroll
            for (int i = 0; i < 32; ++i)
                v[i] = __hip_atomic_load((u64*)(Ht + (i << 10)) + tid,
                                         __ATOMIC_RELAXED, __HIP_MEMORY_SCOPE_AGENT);
            int g = tid >> 1, hf = tid & 1;
#pragma unroll
            for (int i = 0; i < 32; ++i)
                *(u64*)((char*)hl + (i << 11) + (((g ^ (i & 7)) << 4) | (hf << 3))) = v[i];
        }
        __syncthreads();
    }
}

// -------- Phase 2: big output GEMM  C = H @ WhoT^T + b_o --------------------
// A: (4096,1024) bf16; B: (32000,1024) bf16 (N x K); C: (4096,32000) f32.
// 128x128 tile, BK=32, 4 waves (2x2). LDSTRIDE=32: every ds_write/ds_read
// footprint is a contiguous block -> bank-conflict-free floor.
#define LDSTRIDE 32
__global__ __launch_bounds__(256) void gemm_out(
    const short* __restrict__ A,
    const short* __restrict__ B,
    const float* __restrict__ bo,
    float* __restrict__ C)
{
    __shared__ short As[128 * LDSTRIDE];
    __shared__ short Bs[128 * LDSTRIDE];

    int nwg = gridDim.x;
    int cpx = nwg >> 3;
    int bid = blockIdx.x;
    int swz = (bid & 7) * cpx + (bid >> 3);
    int bm = swz % 32;
    int bn = swz / 32;

    int tid = threadIdx.x;
    int lane = tid & 63;
    int wid = tid >> 6;
    int wm = wid >> 1, wn = wid & 1;
    int lrow = lane & 15, kg = lane >> 4;

    f32x4 acc[4][4] = {};

    const size_t a_row0 = (size_t)bm * 128;
    const size_t b_row0 = (size_t)bn * 128;
    int r0 = tid >> 2;
    int c0 = (tid & 3) * 8;

    for (int kk = 0; kk < HIDDEN; kk += 32) {
        bf8v va0 = *(const bf8v*)&A[(a_row0 + r0) * HIDDEN + kk + c0];
        bf8v va1 = *(const bf8v*)&A[(a_row0 + 64 + r0) * HIDDEN + kk + c0];
        bf8v vb0 = *(const bf8v*)&B[(b_row0 + r0) * HIDDEN + kk + c0];
        bf8v vb1 = *(const bf8v*)&B[(b_row0 + 64 + r0) * HIDDEN + kk + c0];
        __syncthreads();
        *(bf8v*)&As[r0 * LDSTRIDE + c0] = va0;
        *(bf8v*)&As[(64 + r0) * LDSTRIDE + c0] = va1;
        *(bf8v*)&Bs[r0 * LDSTRIDE + c0] = vb0;
        *(bf8v*)&Bs[(64 + r0) * LDSTRIDE + c0] = vb1;
        __syncthreads();

        bf8v af[4], bfr[4];
#pragma unroll
        for (int mi = 0; mi < 4; ++mi)
            af[mi] = *(const bf8v*)&As[(wm * 64 + mi * 16 + lrow) * LDSTRIDE + kg * 8];
#pragma unroll
        for (int nj = 0; nj < 4; ++nj)
            bfr[nj] = *(const bf8v*)&Bs[(wn * 64 + nj * 16 + lrow) * LDSTRIDE + kg * 8];
#pragma unroll
        for (int mi = 0; mi < 4; ++mi)
#pragma unroll
            for (int nj = 0; nj < 4; ++nj)
                acc[mi][nj] = __builtin_amdgcn_mfma_f32_16x16x32_bf16(
                    af[mi], bfr[nj], acc[mi][nj], 0, 0, 0);
    }

    size_t crow_base = a_row0 + wm * 64;
    int ccol_base = (int)b_row0 + wn * 64;
#pragma unroll
    for (int nj = 0; nj < 4; ++nj) {
        int col = ccol_base + nj * 16 + lrow;
        float bias = bo[col];
#pragma unroll
        for (int mi = 0; mi < 4; ++mi) {
#pragma unroll
            for (int r = 0; r < 4; ++r) {
                size_t row = crow_base + mi * 16 + kg * 4 + r;
                C[row * VOCAB + col] = acc[mi][nj][r] + bias;
            }
        }
    }
}

// -------- final_state: bf16 h_127 -> f32 ------------------------------------
__global__ __launch_bounds__(256) void write_final(
    const short* __restrict__ Hlast, float* __restrict__ out) {
    int i = blockIdx.x * 256 + threadIdx.x;
    if (i < BATCH * HIDDEN) out[i] = bf2f(Hlast[i]);
}

extern "C" void kernel_launch(void* const* d_in, const int* in_sizes, int n_in,
                              void* d_out, int out_size, void* d_ws, size_t ws_size,
                              hipStream_t stream) {
    const int*   x   = (const int*)  d_in[0];
    const float* st  = (const float*)d_in[1];
    const float* Wxh = (const float*)d_in[2];
    const float* Whh = (const float*)d_in[3];
    const float* bh  = (const float*)d_in[4];
    const float* Who = (const float*)d_in[5];
    const float* bo  = (const float*)d_in[6];
    float* out = (float*)d_out;

    char* ws = (char*)d_ws;
    short* WhhT = (short*)ws;                                           // 2 MB
    short* WhoT = (short*)(ws + 2097152ull);                            // 65.536 MB
    short* H    = (short*)(ws + 2097152ull + 65536000ull);              // 8.389 MB
    short* S0   = (short*)(ws + 2097152ull + 65536000ull + 8388608ull); // 64 KB
    unsigned int* bar = (unsigned int*)(ws + 2097152ull + 65536000ull + 8388608ull + 65536ull);

    transpose_f32_bf16<<<(1024/64)*(1024/64), 256, 0, stream>>>(Whh, WhhT, 1024, 1024);
    transpose_f32_bf16<<<(VOCAB/64)*(1024/64), 256, 0, stream>>>(Who, WhoT, 1024, VOCAB);
    f32_to_bf16_vec<<<(BATCH*HIDDEN + 255)/256, 256, 0, stream>>>(st, S0, BATCH*HIDDEN);
    hipMemsetAsync(bar, 0, sizeof(unsigned int), stream);

    rnn_persistent<<<NBLK, 256, 0, stream>>>(WhhT, Wxh, bh, x, S0, H, bar);

    gemm_out<<<(4096/128) * (VOCAB/128), 256, 0, stream>>>(H, WhoT, bo, out);
    write_final<<<(BATCH*HIDDEN + 255)/256, 256, 0, stream>>>(
        H + (size_t)(SEQ - 1) * BATCH * HIDDEN, out + (size_t)SEQ * BATCH * VOCAB);
}